// Round 1
// baseline (2550.847 us; speedup 1.0000x reference)
//
#include <hip/hip_runtime.h>

#define B_  2
#define S_  2048
#define D_  1024
#define H_  16
#define HD_ 64

// ---------------------------------------------------------------------------
// GEMM: C[m][e] = sum_k A[m][k] * W[e][k] + bias[e]
// A: [4096 x 1024] row-major; W: [1024 x 1024] row-major (out,in) -> NT GEMM,
// both operands contiguous along K.
// LAYOUT 0: C row-major [m][e] (stride 1024)
// LAYOUT 1: C is [B,H,S,HD]: e -> (h,hd), m -> (b,s)
// Tile: BM=128, BN=64, BK=16; 256 threads; 8x4 micro-tile per thread.
// ---------------------------------------------------------------------------
template <int LAYOUT>
__device__ __forceinline__ void gemm_body(const float* __restrict__ A,
                                          const float* __restrict__ W,
                                          const float* __restrict__ bias,
                                          float* __restrict__ C)
{
    __shared__ float As[16 * 132];  // As[k][m], padded stride 132
    __shared__ float Bs[16 * 68];   // Bs[k][n], padded stride 68

    const int tid = threadIdx.x;
    const int m0  = blockIdx.x * 128;
    const int n0  = blockIdx.y * 64;

    const int ty = tid >> 4;  // 0..15 -> rows ty*8 .. ty*8+7
    const int tx = tid & 15;  // 0..15 -> cols tx*4 .. tx*4+3

    float acc[8][4];
#pragma unroll
    for (int i = 0; i < 8; ++i)
#pragma unroll
        for (int j = 0; j < 4; ++j) acc[i][j] = 0.f;

    // A tile: 128 rows x 16 k = 512 float4 positions; thread handles p=tid, p=tid+256
    const int ar0 = tid >> 2;          // 0..63
    const int ar1 = ar0 + 64;          // 64..127
    const int ak  = (tid & 3) * 4;     // k offset 0/4/8/12
    // W tile: 64 rows x 16 k = 256 float4 positions; thread handles p=tid
    const int wr = tid >> 2;           // 0..63
    const int wk = (tid & 3) * 4;

    for (int k0 = 0; k0 < 1024; k0 += 16) {
        float4 a0 = *(const float4*)&A[(size_t)(m0 + ar0) * 1024 + k0 + ak];
        float4 a1 = *(const float4*)&A[(size_t)(m0 + ar1) * 1024 + k0 + ak];
        float4 w0 = *(const float4*)&W[(size_t)(n0 + wr) * 1024 + k0 + wk];

        __syncthreads();  // previous iteration's reads complete
        As[(ak + 0) * 132 + ar0] = a0.x;
        As[(ak + 1) * 132 + ar0] = a0.y;
        As[(ak + 2) * 132 + ar0] = a0.z;
        As[(ak + 3) * 132 + ar0] = a0.w;
        As[(ak + 0) * 132 + ar1] = a1.x;
        As[(ak + 1) * 132 + ar1] = a1.y;
        As[(ak + 2) * 132 + ar1] = a1.z;
        As[(ak + 3) * 132 + ar1] = a1.w;
        Bs[(wk + 0) * 68 + wr] = w0.x;
        Bs[(wk + 1) * 68 + wr] = w0.y;
        Bs[(wk + 2) * 68 + wr] = w0.z;
        Bs[(wk + 3) * 68 + wr] = w0.w;
        __syncthreads();

#pragma unroll
        for (int k = 0; k < 16; ++k) {
            float av[8], bv4[4];
            *(float4*)&av[0]  = *(const float4*)&As[k * 132 + ty * 8];
            *(float4*)&av[4]  = *(const float4*)&As[k * 132 + ty * 8 + 4];
            *(float4*)&bv4[0] = *(const float4*)&Bs[k * 68 + tx * 4];
#pragma unroll
            for (int i = 0; i < 8; ++i)
#pragma unroll
                for (int j = 0; j < 4; ++j)
                    acc[i][j] = fmaf(av[i], bv4[j], acc[i][j]);
        }
    }

    float4 bias4 = *(const float4*)&bias[n0 + tx * 4];
#pragma unroll
    for (int r = 0; r < 8; ++r) {
        const int m = m0 + ty * 8 + r;
        float4 out;
        out.x = acc[r][0] + bias4.x;
        out.y = acc[r][1] + bias4.y;
        out.z = acc[r][2] + bias4.z;
        out.w = acc[r][3] + bias4.w;
        if (LAYOUT == 0) {
            *(float4*)&C[(size_t)m * 1024 + n0 + tx * 4] = out;
        } else {
            const int b = m >> 11, s = m & 2047;
            const int h = n0 >> 6;  // BN=64 == HD, head-aligned
            *(float4*)&C[((size_t)(b * H_ + h) * S_ + s) * HD_ + tx * 4] = out;
        }
    }
}

__global__ __launch_bounds__(256) void qkv_gemm(
    const float* __restrict__ q_in, const float* __restrict__ k_in,
    const float* __restrict__ v_in, const float* __restrict__ Wq,
    const float* __restrict__ bq, const float* __restrict__ Wk,
    const float* __restrict__ bk, const float* __restrict__ Wv,
    const float* __restrict__ bv, float* __restrict__ Qb,
    float* __restrict__ Kb, float* __restrict__ Vb)
{
    const int z = blockIdx.z;
    const float *A, *W, *bias;
    float* C;
    if (z == 0)      { A = q_in; W = Wq; bias = bq; C = Qb; }
    else if (z == 1) { A = k_in; W = Wk; bias = bk; C = Kb; }
    else             { A = v_in; W = Wv; bias = bv; C = Vb; }
    gemm_body<1>(A, W, bias, C);
}

__global__ __launch_bounds__(256) void out_gemm(
    const float* __restrict__ A, const float* __restrict__ W,
    const float* __restrict__ bias, float* __restrict__ C)
{
    gemm_body<0>(A, W, bias, C);
}

// ---------------------------------------------------------------------------
// Attention: one workgroup per (b, h, 8 q-rows).
// Full 8x2048 fp32 score tile lives in exactly 64 KB static LDS.
// The 512-float Q tile is parked in lds[7*2048+1536 .. 16384) (== the storage
// of scores[7][1536..2047]); those 512 scores are computed into registers
// first and written back after Q is dead.
// Softmax per row via 32-lane shuffles; attn written once; PV fused.
// ---------------------------------------------------------------------------
__global__ __launch_bounds__(256) void attn_kernel(
    const float* __restrict__ Qb, const float* __restrict__ Kb,
    const float* __restrict__ Vb, const int* __restrict__ mask,
    float* __restrict__ attnOut, float* __restrict__ Xc)
{
    __shared__ float lds[8 * 2048];  // 64 KB
    const int tid = threadIdx.x;
    const int q0  = blockIdx.x * 8;
    const int h   = blockIdx.y;
    const int b   = blockIdx.z;

    const size_t bh = (size_t)(b * H_ + h);
    const float* Qh = Qb + bh * S_ * HD_;
    const float* Kh = Kb + bh * S_ * HD_;
    const float* Vh = Vb + bh * S_ * HD_;
    float* qlds = &lds[7 * 2048 + 1536];  // q[r][d] at qlds[r*64+d]

    // phase 0: stage Q tile (8x64) into tail of LDS
    for (int i = tid; i < 512; i += 256) qlds[i] = Qh[(size_t)q0 * 64 + i];
    __syncthreads();

    // phase 1: scores[7][1536..2047] -> registers (their LDS home holds Q)
    float s7[2];
#pragma unroll
    for (int v = 0; v < 2; ++v) {
        const int c = 1536 + v * 256 + tid;
        const float* kp = Kh + (size_t)c * 64;
        float acc = 0.f;
#pragma unroll 4
        for (int dq = 0; dq < 16; ++dq) {
            float4 kv = *(const float4*)&kp[dq * 4];
            float4 q4 = *(const float4*)&qlds[7 * 64 + dq * 4];
            acc = fmaf(kv.x, q4.x, acc);
            acc = fmaf(kv.y, q4.y, acc);
            acc = fmaf(kv.z, q4.z, acc);
            acc = fmaf(kv.w, q4.w, acc);
        }
        float s = acc * 0.125f;
        if (mask[b * S_ + c] == 0) s = -1e9f;
        s7[v] = s;
    }

    // phase 2: all 8 rows, columns processed in pairs (c, c+256)
    for (int u = 0; u < 4; ++u) {
        const int c0 = tid + u * 512;
        const int c1 = c0 + 256;
        const float* kp0 = Kh + (size_t)c0 * 64;
        const float* kp1 = Kh + (size_t)c1 * 64;
        float acc0[8], acc1[8];
#pragma unroll
        for (int r = 0; r < 8; ++r) { acc0[r] = 0.f; acc1[r] = 0.f; }
#pragma unroll 4
        for (int dq = 0; dq < 16; ++dq) {
            float4 k0v = *(const float4*)&kp0[dq * 4];
            float4 k1v = *(const float4*)&kp1[dq * 4];
#pragma unroll
            for (int r = 0; r < 8; ++r) {
                float4 q4 = *(const float4*)&qlds[r * 64 + dq * 4];
                acc0[r] = fmaf(k0v.x, q4.x, acc0[r]);
                acc0[r] = fmaf(k0v.y, q4.y, acc0[r]);
                acc0[r] = fmaf(k0v.z, q4.z, acc0[r]);
                acc0[r] = fmaf(k0v.w, q4.w, acc0[r]);
                acc1[r] = fmaf(k1v.x, q4.x, acc1[r]);
                acc1[r] = fmaf(k1v.y, q4.y, acc1[r]);
                acc1[r] = fmaf(k1v.z, q4.z, acc1[r]);
                acc1[r] = fmaf(k1v.w, q4.w, acc1[r]);
            }
        }
        const int mq0 = mask[b * S_ + c0];
        const int mq1 = mask[b * S_ + c1];
#pragma unroll
        for (int r = 0; r < 8; ++r) {
            const float v0 = mq0 ? acc0[r] * 0.125f : -1e9f;
            const float v1 = mq1 ? acc1[r] * 0.125f : -1e9f;
            if (!(r == 7 && c0 >= 1536)) lds[r * 2048 + c0] = v0;
            if (!(r == 7 && c1 >= 1536)) lds[r * 2048 + c1] = v1;
        }
    }
    __syncthreads();  // all Q reads done; safe to overwrite Q region

    // phase 3: land the held row-7 tail scores
    lds[7 * 2048 + 1536 + tid] = s7[0];
    lds[7 * 2048 + 1792 + tid] = s7[1];
    __syncthreads();

    // phase 4: softmax per row (32 lanes per row) + write attn
    {
        const int r = tid >> 5;
        const int l = tid & 31;
        float* row = &lds[r * 2048];
        float mx = -1e30f;
        for (int c = l; c < 2048; c += 32) mx = fmaxf(mx, row[c]);
#pragma unroll
        for (int off = 16; off >= 1; off >>= 1) mx = fmaxf(mx, __shfl_xor(mx, off, 32));
        float sum = 0.f;
        for (int c = l; c < 2048; c += 32) {
            const float e = __expf(row[c] - mx);
            row[c] = e;
            sum += e;
        }
#pragma unroll
        for (int off = 16; off >= 1; off >>= 1) sum += __shfl_xor(sum, off, 32);
        const float inv = 1.f / sum;
        float* arow = attnOut + (bh * S_ + (size_t)(q0 + r)) * S_;
        for (int c = l; c < 2048; c += 32) {
            const float p = row[c] * inv;
            row[c]  = p;
            arow[c] = p;
        }
    }
    __syncthreads();

    // phase 5: PV — thread (g,d) accumulates rows {g, g+4} at column d
    {
        const int g = tid >> 6;
        const int d = tid & 63;
        const float* r0 = &lds[g * 2048];
        const float* r1 = &lds[(g + 4) * 2048];
        float a0 = 0.f, a1 = 0.f;
        for (int c = 0; c < 2048; c += 4) {
            float4 p0 = *(const float4*)&r0[c];
            float4 p1 = *(const float4*)&r1[c];
            const float v0 = Vh[(size_t)(c + 0) * 64 + d];
            const float v1 = Vh[(size_t)(c + 1) * 64 + d];
            const float v2 = Vh[(size_t)(c + 2) * 64 + d];
            const float v3 = Vh[(size_t)(c + 3) * 64 + d];
            a0 = fmaf(p0.x, v0, a0); a0 = fmaf(p0.y, v1, a0);
            a0 = fmaf(p0.z, v2, a0); a0 = fmaf(p0.w, v3, a0);
            a1 = fmaf(p1.x, v0, a1); a1 = fmaf(p1.y, v1, a1);
            a1 = fmaf(p1.z, v2, a1); a1 = fmaf(p1.w, v3, a1);
        }
        Xc[((size_t)b * S_ + q0 + g) * D_ + h * HD_ + d]     = a0;
        Xc[((size_t)b * S_ + q0 + g + 4) * D_ + h * HD_ + d] = a1;
    }
}

extern "C" void kernel_launch(void* const* d_in, const int* in_sizes, int n_in,
                              void* d_out, int out_size, void* d_ws, size_t ws_size,
                              hipStream_t stream)
{
    const float* query = (const float*)d_in[0];
    const float* key   = (const float*)d_in[1];
    const float* value = (const float*)d_in[2];
    const int*   mask  = (const int*)d_in[3];
    const float* Wq = (const float*)d_in[4];
    const float* bq = (const float*)d_in[5];
    const float* Wk = (const float*)d_in[6];
    const float* bk = (const float*)d_in[7];
    const float* Wv = (const float*)d_in[8];
    const float* bv = (const float*)d_in[9];
    const float* Wo = (const float*)d_in[10];
    const float* bo = (const float*)d_in[11];

    float* out_x   = (float*)d_out;                      // [B,S,D]
    float* out_att = (float*)d_out + (size_t)B_ * S_ * D_;  // [B,H,S,S]

    float* ws = (float*)d_ws;
    const size_t seg = (size_t)B_ * S_ * D_;  // 4,194,304 floats
    float* Qb = ws;            // [B,H,S,HD]
    float* Kb = Qb + seg;
    float* Vb = Kb + seg;
    float* Xc = Vb + seg;      // [B,S,D] = attn @ V, head-concat layout

    dim3 blk(256);
    qkv_gemm<<<dim3(32, 16, 3), blk, 0, stream>>>(query, key, value,
                                                  Wq, bq, Wk, bk, Wv, bv,
                                                  Qb, Kb, Vb);
    attn_kernel<<<dim3(S_ / 8, H_, B_), blk, 0, stream>>>(Qb, Kb, Vb, mask,
                                                          out_att, Xc);
    out_gemm<<<dim3(32, 16, 1), blk, 0, stream>>>(Xc, Wo, bo, out_x);
}